// Round 7
// baseline (7862.067 us; speedup 1.0000x reference)
//
#include <hip/hip_runtime.h>
#include <float.h>
#include <type_traits>

#define BB 8
#define NN 2048
#define KNN 20

__device__ __forceinline__ float leaky(float v) { return fmaxf(v, 0.2f * v); }

// ---------- transpose x (B,3,N) -> xt (B,N,3) ----------
__global__ void k_transpose_x(const float* __restrict__ x, float* __restrict__ xt) {
    int i = blockIdx.x * 256 + threadIdx.x;
    if (i >= BB * NN * 3) return;
    int c = i % 3; int n = (i / 3) % NN; int b = i / (3 * NN);
    xt[i] = x[((size_t)b * 3 + c) * NN + n];
}

// ---------- LDS-tiled transpose w (CO,CI) -> wt (CI,CO), 64x64 tiles ----------
__global__ __launch_bounds__(256) void k_transpose_w_tiled(const float* __restrict__ w,
                                                           float* __restrict__ wt,
                                                           int CO, int CI) {
    __shared__ float tile[64][65];
    int o0 = blockIdx.x * 64;
    int c0 = blockIdx.y * 64;
    int tid = threadIdx.x;
    for (int i = tid; i < 64 * 64; i += 256) {
        int r = i >> 6, c = i & 63;
        tile[r][c] = w[(size_t)(o0 + r) * CI + c0 + c];
    }
    __syncthreads();
    for (int i = tid; i < 64 * 64; i += 256) {
        int cc = i >> 6, oo = i & 63;
        wt[(size_t)(c0 + cc) * CO + o0 + oo] = tile[oo][cc];
    }
}

// ---------- all 4 edgeconv weight splits in ONE dispatch ----------
__device__ __forceinline__ void wpair_one(const float* __restrict__ w, float* __restrict__ wtA,
                                          float* __restrict__ wtD, int CO, int CI, int i) {
    int o = i / CI, c = i % CI;
    float a = w[(size_t)o * 2 * CI + c];
    float bb = w[(size_t)o * 2 * CI + CI + c];
    wtA[c * CO + o] = a;
    wtD[c * CO + o] = bb - a;
}
__global__ void k_wpair_all(const float* w1, const float* w2, const float* w3, const float* w4,
                            float* A1, float* D1, float* A2, float* D2,
                            float* A3, float* D3, float* A4, float* D4) {
    int i = blockIdx.x * 256 + threadIdx.x;
    if (i < 192)            { wpair_one(w1, A1, D1, 64, 3, i); }
    else if (i < 4288)      { wpair_one(w2, A2, D2, 64, 64, i - 192); }
    else if (i < 12480)     { wpair_one(w3, A3, D3, 128, 64, i - 4288); }
    else if (i < 45248)     { wpair_one(w4, A4, D4, 256, 128, i - 12480); }
}

// ---------- squared norms per point ----------
template<int C>
__global__ void k_xx(const float* __restrict__ F, int FS, float* __restrict__ xx) {
    int i = blockIdx.x * 256 + threadIdx.x;
    if (i >= BB * NN) return;
    const float* r = F + (size_t)i * FS;
    float s = 0.f;
    #pragma unroll
    for (int c = 0; c < C; ++c) { float v = r[c]; s += v * v; }
    xx[i] = s;
}

// ---------- FUSED KNN: per block = 64 query rows x 512 cols (one quarter),
// distances tiled 64x64 in LDS, per-row top-20 maintained by threshold-gated
// insertion (ascending j scan preserves lax.top_k tie order).
// LDS strides: Dl 66 (2-way free), lists 21 (conflict-free for 16-row groups). ----------
template<int C>
__global__ __launch_bounds__(256) void k_knnf(const float* __restrict__ F, int FS,
                                              const float* __restrict__ xx,
                                              float* __restrict__ plv, int* __restrict__ pli) {
    constexpr int CCH = (C >= 32) ? 32 : C;
    constexpr int NCH = (C + CCH - 1) / CCH;
    __shared__ __align__(16) float Xi[CCH * 64];
    __shared__ __align__(16) float Xj[CCH * 64];
    __shared__ float Dl[64 * 66];
    __shared__ float lv[64 * 21];
    __shared__ int   li[64 * 21];
    int tid = threadIdx.x;
    int ty = tid >> 4, tx = tid & 15;
    int q = blockIdx.x & 3;
    int slab = (blockIdx.x >> 2) & 31;
    int b = blockIdx.x >> 7;
    int i0 = slab * 64;
    const float* Fb = F + (size_t)b * NN * FS;
    const float* xxb = xx + (size_t)b * NN;
    for (int t = tid; t < 64 * 21; t += 256) { lv[t] = -FLT_MAX; li[t] = 0x7fffffff; }
    float xxi[4];
    #pragma unroll
    for (int r = 0; r < 4; ++r) xxi[r] = xxb[i0 + 4 * ty + r];
    int lane = tid & 63, wv = tid >> 6;
    int mrow = wv * 16 + (lane & 15);
    __syncthreads();
    for (int tile = 0; tile < 8; ++tile) {
        int j0 = q * 512 + tile * 64;
        float acc[4][4] = {};
        for (int ch = 0; ch < NCH; ++ch) {
            int cb = ch * CCH;
            __syncthreads();   // protects Xi/Xj (prev FMA) and Dl/lists (prev merge)
            if constexpr (CCH % 4 == 0) {
                for (int t = tid; t < 64 * (CCH / 4); t += 256) {
                    int r = t & 63, cc = t >> 6;
                    float vi[4], vj[4];
                    *(float4*)vi = *(const float4*)(Fb + (size_t)(i0 + r) * FS + cb + 4 * cc);
                    *(float4*)vj = *(const float4*)(Fb + (size_t)(j0 + r) * FS + cb + 4 * cc);
                    #pragma unroll
                    for (int u = 0; u < 4; ++u) {
                        Xi[(4 * cc + u) * 64 + r] = vi[u];
                        Xj[(4 * cc + u) * 64 + r] = vj[u];
                    }
                }
            } else {
                for (int t = tid; t < 64 * CCH; t += 256) {
                    int r = t & 63, c = t >> 6;
                    Xi[c * 64 + r] = Fb[(size_t)(i0 + r) * FS + cb + c];
                    Xj[c * 64 + r] = Fb[(size_t)(j0 + r) * FS + cb + c];
                }
            }
            __syncthreads();
            for (int c = 0; c < CCH; ++c) {
                float a[4], bv[4];
                *(float4*)a  = *(const float4*)&Xi[c * 64 + 4 * ty];
                *(float4*)bv = *(const float4*)&Xj[c * 64 + 4 * tx];
                #pragma unroll
                for (int r = 0; r < 4; ++r)
                    #pragma unroll
                    for (int s = 0; s < 4; ++s) acc[r][s] += a[r] * bv[s];
            }
        }
        float xxj[4];
        #pragma unroll
        for (int s = 0; s < 4; ++s) xxj[s] = xxb[j0 + 4 * tx + s];
        #pragma unroll
        for (int r = 0; r < 4; ++r)
            #pragma unroll
            for (int s = 0; s < 4; ++s)
                Dl[(4 * ty + r) * 66 + 4 * tx + s] = 2.f * acc[r][s] - xxi[r] - xxj[s];
        __syncthreads();
        if (lane < 16) {   // 16 active lanes per wave, one row each
            int r = mrow;
            float* LV = &lv[r * 21];
            int*   LI = &li[r * 21];
            float thr = LV[19]; int thrI = LI[19];
            const float* Dr = &Dl[r * 66];
            for (int j = 0; j < 64; ++j) {
                float v = Dr[j];
                int gj = j0 + j;
                if (v > thr || (v == thr && gj < thrI)) {
                    int p = 19;
                    while (p > 0) {
                        float pv = LV[p - 1]; int pi = LI[p - 1];
                        if (!(v > pv || (v == pv && gj < pi))) break;
                        LV[p] = pv; LI[p] = pi; --p;
                    }
                    LV[p] = v; LI[p] = gj;
                    thr = LV[19]; thrI = LI[19];
                }
            }
        }
        // next tile's first barrier protects Dl/lists
    }
    __syncthreads();
    if (tid < 64) {
        size_t base = (((size_t)b * NN + i0 + tid) * 4 + q) * KNN;
        for (int k = 0; k < KNN; ++k) {
            plv[base + k] = lv[tid * 21 + k];
            pli[base + k] = li[tid * 21 + k];
        }
    }
}

// ---------- merge 4 quarter top-20 lists -> final top-20 indices ----------
__global__ void k_kmerge(const float* __restrict__ plv, const int* __restrict__ pli,
                         int* __restrict__ idxo) {
    int i = blockIdx.x * 256 + threadIdx.x;   // b*NN + n
    if (i >= BB * NN) return;
    const float* V = plv + (size_t)i * 4 * KNN;
    const int*   I = pli + (size_t)i * 4 * KNN;
    int p[4] = {0, KNN, 2 * KNN, 3 * KNN};
    int e[4] = {KNN, 2 * KNN, 3 * KNN, 4 * KNN};
    int* op = idxo + (size_t)i * KNN;
    for (int k = 0; k < KNN; ++k) {
        float bv = -FLT_MAX; int bi = 0x7fffffff; int bq = 0;
        #pragma unroll
        for (int q = 0; q < 4; ++q) {
            if (p[q] < e[q]) {
                float v = V[p[q]]; int ii = I[p[q]];
                if (v > bv || (v == bv && ii < bi)) { bv = v; bi = ii; bq = q; }
            }
        }
        op[k] = bi; p[bq]++;
    }
}

// ---------- pair GEMM: Y = F*wtA (chunk buffer), C2 = F*wtD -> written straight
// into the layer's xcat output slot (stride 512); gather later reads+overwrites it ----------
template<int CIN, int COUT>
__global__ __launch_bounds__(256) void k_gemm_pair(const float* __restrict__ F, int FS, int b0,
    const float* __restrict__ wtA, const float* __restrict__ wtD,
    float* __restrict__ Y, float* __restrict__ c2x) {
    constexpr int CCH = (CIN >= 32) ? 32 : CIN;
    constexpr int NCH = CIN / CCH;
    __shared__ __align__(16) float Xi[CCH * 64];
    __shared__ __align__(16) float Wa[CCH * 64];
    __shared__ __align__(16) float Wd[CCH * 64];
    int tid = threadIdx.x;
    int r0 = blockIdx.x * 64;            // chunk-local row
    int c0 = blockIdx.y * 64;
    int b = b0 + r0 / NN;
    int n0 = r0 % NN;
    const float* Fb = F + ((size_t)b * NN + n0) * FS;
    int ty = tid >> 4, tx = tid & 15;
    float accY[4][4] = {}, accD[4][4] = {};
    for (int ch = 0; ch < NCH; ++ch) {
        int cb = ch * CCH;
        if (ch) __syncthreads();
        if constexpr (CCH % 4 == 0) {
            for (int t = tid; t < 64 * (CCH / 4); t += 256) {
                int r = t & 63, cc = t >> 6;
                float v[4];
                *(float4*)v = *(const float4*)(Fb + (size_t)r * FS + cb + 4 * cc);
                #pragma unroll
                for (int u = 0; u < 4; ++u) Xi[(4 * cc + u) * 64 + r] = v[u];
            }
            for (int t = tid; t < CCH * 16; t += 256) {
                int c = t >> 4, q = t & 15;
                *(float4*)&Wa[c * 64 + 4 * q] = *(const float4*)(wtA + (size_t)(cb + c) * COUT + c0 + 4 * q);
                *(float4*)&Wd[c * 64 + 4 * q] = *(const float4*)(wtD + (size_t)(cb + c) * COUT + c0 + 4 * q);
            }
        } else {
            for (int t = tid; t < 64 * CCH; t += 256) {
                int r = t & 63, c = t >> 6;
                Xi[c * 64 + r] = Fb[(size_t)r * FS + cb + c];
            }
            for (int t = tid; t < CCH * 64; t += 256) {
                int col = t & 63, c = t >> 6;
                Wa[c * 64 + col] = wtA[(size_t)(cb + c) * COUT + c0 + col];
                Wd[c * 64 + col] = wtD[(size_t)(cb + c) * COUT + c0 + col];
            }
        }
        __syncthreads();
        for (int c = 0; c < CCH; ++c) {
            float a[4], wa[4], wd[4];
            *(float4*)a  = *(const float4*)&Xi[c * 64 + 4 * ty];
            *(float4*)wa = *(const float4*)&Wa[c * 64 + 4 * tx];
            *(float4*)wd = *(const float4*)&Wd[c * 64 + 4 * tx];
            #pragma unroll
            for (int r = 0; r < 4; ++r)
                #pragma unroll
                for (int s = 0; s < 4; ++s) {
                    accY[r][s] += a[r] * wa[s];
                    accD[r][s] += a[r] * wd[s];
                }
        }
    }
    #pragma unroll
    for (int r = 0; r < 4; ++r) {
        *(float4*)(Y + (size_t)(r0 + 4 * ty + r) * COUT + c0 + 4 * tx) = *(float4*)accY[r];
        *(float4*)(c2x + ((size_t)b0 * NN + r0 + 4 * ty + r) * 512 + c0 + 4 * tx) = *(float4*)accD[r];
    }
}

// ---------- gather-max: io slot holds C2 on entry, final features on exit ----------
template<int COUT>
__global__ __launch_bounds__(256) void k_gather(const float* __restrict__ Y,
    const int* __restrict__ idx, const float* __restrict__ sc, const float* __restrict__ bi,
    float* io, int b0) {
    constexpr int LPP = COUT / 4;
    constexpr int PPW = 64 / LPP;
    constexpr int PPB = 4 * PPW;
    int tid = threadIdx.x;
    int lane = tid & 63, wv = tid >> 6;
    int pl = blockIdx.x * PPB + wv * PPW + lane / LPP;   // chunk-local point
    int bl = pl / NN, n = pl % NN;
    int o0 = 4 * (lane % LPP);
    float* iop = io + ((size_t)(b0 + bl) * NN + n) * 512 + o0;
    float c2[4], s4[4], b4[4];
    *(float4*)c2 = *(const float4*)iop;
    *(float4*)s4 = *(const float4*)(sc + o0);
    *(float4*)b4 = *(const float4*)(bi + o0);
    const int* ip = idx + ((size_t)(b0 + bl) * NN + n) * KNN;
    const float* Yb = Y + (size_t)bl * NN * COUT;
    float mx[4] = {-FLT_MAX, -FLT_MAX, -FLT_MAX, -FLT_MAX};
    for (int k = 0; k < KNN; ++k) {
        int m = ip[k];
        float y[4];
        *(float4*)y = *(const float4*)(Yb + (size_t)m * COUT + o0);
        #pragma unroll
        for (int u = 0; u < 4; ++u) {
            float v = (y[u] + c2[u]) * s4[u] + b4[u];
            mx[u] = fmaxf(mx[u], leaky(v));
        }
    }
    *(float4*)iop = *(float4*)mx;
}

// ---------- conv5: 128x128 tile, 8x8 micro-tile, fused partial pooling ----------
__global__ __launch_bounds__(256) void k_conv5(const float* __restrict__ xcat,
    const float* __restrict__ w5t, const float* __restrict__ s5, const float* __restrict__ b5,
    float* __restrict__ pmax, float* __restrict__ psum) {
    __shared__ __align__(16) float Xi[32 * 128];
    __shared__ __align__(16) float Wj[32 * 128];
    int tid = threadIdx.x;
    int ty = tid >> 4, tx = tid & 15;
    int r0 = blockIdx.x * 128;
    int col0 = blockIdx.y * 128;
    int b = r0 / NN, tileInB = (r0 % NN) / 128;
    const float* Fb = xcat + (size_t)r0 * 512;
    float acc[8][8] = {};
    for (int ch = 0; ch < 16; ++ch) {
        int cb = ch * 32;
        if (ch) __syncthreads();
        for (int t = tid; t < 128 * 8; t += 256) {
            int r = t & 127, cc = t >> 7;
            float v[4];
            *(float4*)v = *(const float4*)(Fb + (size_t)r * 512 + cb + 4 * cc);
            #pragma unroll
            for (int u = 0; u < 4; ++u) Xi[(4 * cc + u) * 128 + r] = v[u];
        }
        for (int t = tid; t < 32 * 32; t += 256) {
            int c = t >> 5, q = t & 31;
            *(float4*)&Wj[c * 128 + 4 * q] = *(const float4*)(w5t + (size_t)(cb + c) * 1024 + col0 + 4 * q);
        }
        __syncthreads();
        for (int c = 0; c < 32; ++c) {
            float a0[4], a1[4], w0[4], w1[4];
            *(float4*)a0 = *(const float4*)&Xi[c * 128 + 4 * ty];
            *(float4*)a1 = *(const float4*)&Xi[c * 128 + 64 + 4 * ty];
            *(float4*)w0 = *(const float4*)&Wj[c * 128 + 4 * tx];
            *(float4*)w1 = *(const float4*)&Wj[c * 128 + 64 + 4 * tx];
            #pragma unroll
            for (int r = 0; r < 4; ++r)
                #pragma unroll
                for (int u = 0; u < 4; ++u) {
                    acc[r][u]         += a0[r] * w0[u];
                    acc[r][4 + u]     += a0[r] * w1[u];
                    acc[4 + r][u]     += a1[r] * w0[u];
                    acc[4 + r][4 + u] += a1[r] * w1[u];
                }
        }
    }
    float hmx[2][4], hsm[2][4];
    #pragma unroll
    for (int h = 0; h < 2; ++h)
        #pragma unroll
        for (int u = 0; u < 4; ++u) { hmx[h][u] = -FLT_MAX; hsm[h][u] = 0.f; }
    #pragma unroll
    for (int h = 0; h < 2; ++h)
        #pragma unroll
        for (int u = 0; u < 4; ++u) {
            int o = col0 + 64 * h + 4 * tx + u;
            float sv = s5[o], bv = b5[o];
            #pragma unroll
            for (int r = 0; r < 8; ++r) {
                float hh = leaky(acc[r][4 * h + u] * sv + bv);
                hmx[h][u] = fmaxf(hmx[h][u], hh);
                hsm[h][u] += hh;
            }
        }
    __syncthreads();
    float* redM = Xi;
    float* redS = Wj;
    #pragma unroll
    for (int h = 0; h < 2; ++h) {
        *(float4*)&redM[ty * 128 + 64 * h + 4 * tx] = *(float4*)hmx[h];
        *(float4*)&redS[ty * 128 + 64 * h + 4 * tx] = *(float4*)hsm[h];
    }
    __syncthreads();
    for (int s = 8; s > 0; s >>= 1) {
        if (ty < s) {
            #pragma unroll
            for (int h = 0; h < 2; ++h) {
                int c = 64 * h + 4 * tx;
                float m0[4], m1[4], s0[4], s1[4];
                *(float4*)m0 = *(float4*)&redM[ty * 128 + c];
                *(float4*)m1 = *(float4*)&redM[(ty + s) * 128 + c];
                *(float4*)s0 = *(float4*)&redS[ty * 128 + c];
                *(float4*)s1 = *(float4*)&redS[(ty + s) * 128 + c];
                #pragma unroll
                for (int u = 0; u < 4; ++u) { m0[u] = fmaxf(m0[u], m1[u]); s0[u] += s1[u]; }
                *(float4*)&redM[ty * 128 + c] = *(float4*)m0;
                *(float4*)&redS[ty * 128 + c] = *(float4*)s0;
            }
        }
        __syncthreads();
    }
    if (ty == 0) {
        #pragma unroll
        for (int h = 0; h < 2; ++h) {
            int c = 64 * h + 4 * tx;
            size_t o = ((size_t)b * 16 + tileInB) * 1024 + col0 + c;
            *(float4*)&pmax[o] = *(float4*)&redM[c];
            *(float4*)&psum[o] = *(float4*)&redS[c];
        }
    }
}

__global__ void k_poolreduce(const float* __restrict__ pmax, const float* __restrict__ psum,
                             float* __restrict__ pooled) {
    int i = blockIdx.x * 256 + threadIdx.x;
    if (i >= BB * 1024) return;
    int b = i / 1024, o = i % 1024;
    float mx = -FLT_MAX, sm = 0.f;
    for (int ch = 0; ch < 16; ++ch) {
        mx = fmaxf(mx, pmax[((size_t)b * 16 + ch) * 1024 + o]);
        sm += psum[((size_t)b * 16 + ch) * 1024 + o];
    }
    pooled[(size_t)b * 2048 + o] = mx;
    pooled[(size_t)b * 2048 + 1024 + o] = sm / (float)NN;
}

// ---------- FC: wave-per-output, coalesced float4 weight reads, shfl reduce ----------
template<int CI, bool SCALE, bool RELU>
__global__ __launch_bounds__(256) void k_fcw(const float* __restrict__ in,
                                             const float* __restrict__ w,
                                             const float* __restrict__ sc,
                                             const float* __restrict__ bi,
                                             float* __restrict__ out, int CO) {
    int wv = (blockIdx.x << 2) + (threadIdx.x >> 6);
    int lane = threadIdx.x & 63;
    int o = wv % CO, b = wv / CO;
    const float* ir = in + (size_t)b * CI;
    const float* wr = w + (size_t)o * CI;
    float acc = 0.f;
    #pragma unroll
    for (int q = 0; q < CI / 256; ++q) {
        int ofs = q * 256 + 4 * lane;
        float4 wv4 = *(const float4*)(wr + ofs);
        float4 iv4 = *(const float4*)(ir + ofs);
        acc += wv4.x * iv4.x + wv4.y * iv4.y + wv4.z * iv4.z + wv4.w * iv4.w;
    }
    #pragma unroll
    for (int s = 1; s < 64; s <<= 1) acc += __shfl_xor(acc, s);
    if (lane == 0) {
        float v = SCALE ? (acc * sc[o] + bi[o]) : (acc + bi[o]);
        if (RELU) v = fmaxf(v, 0.f);
        out[wv] = v;
    }
}

extern "C" void kernel_launch(void* const* d_in, const int* in_sizes, int n_in,
                              void* d_out, int out_size, void* d_ws, size_t ws_size,
                              hipStream_t stream) {
    const float* x    = (const float*)d_in[0];
    const float* w1   = (const float*)d_in[1];
    const float* s1   = (const float*)d_in[2];
    const float* b1   = (const float*)d_in[3];
    const float* w2   = (const float*)d_in[4];
    const float* s2   = (const float*)d_in[5];
    const float* b2   = (const float*)d_in[6];
    const float* w3   = (const float*)d_in[7];
    const float* s3   = (const float*)d_in[8];
    const float* b3   = (const float*)d_in[9];
    const float* w4   = (const float*)d_in[10];
    const float* s4   = (const float*)d_in[11];
    const float* b4   = (const float*)d_in[12];
    const float* w5   = (const float*)d_in[13];
    const float* s5   = (const float*)d_in[14];
    const float* b5   = (const float*)d_in[15];
    const float* fc1w = (const float*)d_in[16];
    const float* s6   = (const float*)d_in[17];
    const float* b6   = (const float*)d_in[18];
    const float* fc2w = (const float*)d_in[19];
    const float* s7   = (const float*)d_in[20];
    const float* b7   = (const float*)d_in[21];
    const float* fc3w = (const float*)d_in[22];
    const float* fc3b = (const float*)d_in[23];
    float* out = (float*)d_out;

    char* ws = (char*)d_ws;
    size_t off = 0;
    auto alloc = [&](size_t bytes) {
        void* p = ws + off;
        off = (off + bytes + 255) & ~(size_t)255;
        return p;
    };
    float* xt   = (float*)alloc((size_t)BB * NN * 3 * 4);
    float* xcat = (float*)alloc((size_t)BB * NN * 512 * 4);
    int*   idx  = (int*)  alloc((size_t)BB * NN * KNN * 4);
    float* xx   = (float*)alloc((size_t)BB * NN * 4);
    float* wtA1 = (float*)alloc(3 * 64 * 4);
    float* wtD1 = (float*)alloc(3 * 64 * 4);
    float* wtA2 = (float*)alloc(64 * 64 * 4);
    float* wtD2 = (float*)alloc(64 * 64 * 4);
    float* wtA3 = (float*)alloc(64 * 128 * 4);
    float* wtD3 = (float*)alloc(64 * 128 * 4);
    float* wtA4 = (float*)alloc(128 * 256 * 4);
    float* wtD4 = (float*)alloc(128 * 256 * 4);
    size_t base_end = off;

    // UNION region: plv/pli (KNN) -> Y (transform) -> head buffers
    size_t avail = ws_size > base_end ? ws_size - base_end : 0;
    char* uni = ws + base_end;
    float* plv = (float*)uni;                               // 16384*80 floats = 5.24 MB
    int*   pli = (int*)(plv + (size_t)BB * NN * 4 * KNN);   // 5.24 MB
    float* w5t    = (float*)uni;
    float* pmax   = w5t + 512 * 1024;
    float* psum   = pmax + (size_t)BB * 16 * 1024;
    float* pooled = psum + (size_t)BB * 16 * 1024;
    float* f1     = pooled + (size_t)BB * 2048;
    float* f2     = f1 + (size_t)BB * 512;

    k_transpose_x<<<(BB * NN * 3 + 255) / 256, 256, 0, stream>>>(x, xt);
    k_wpair_all<<<(45248 + 255) / 256, 256, 0, stream>>>(w1, w2, w3, w4,
        wtA1, wtD1, wtA2, wtD2, wtA3, wtD3, wtA4, wtD4);

    auto layer = [&](auto cTag, auto coTag, const float* F, int FS,
                     const float* wtA, const float* wtD,
                     const float* sc, const float* bi, float* outp) {
        constexpr int C  = decltype(cTag)::value;
        constexpr int CO = decltype(coTag)::value;
        k_xx<C><<<(BB * NN + 255) / 256, 256, 0, stream>>>(F, FS, xx);
        k_knnf<C><<<BB * 32 * 4, 256, 0, stream>>>(F, FS, xx, plv, pli);
        k_kmerge<<<(BB * NN + 255) / 256, 256, 0, stream>>>(plv, pli, idx);
        // transform + gather; Y chunked only if avail is tight
        size_t ypb = (size_t)NN * CO * 4;
        int nbY = (int)(avail / ypb);
        if (nbY < 1) nbY = 1;
        if (nbY > BB) nbY = BB;
        for (int b0 = 0; b0 < BB; b0 += nbY) {
            int nb = BB - b0 < nbY ? BB - b0 : nbY;
            float* Yc = (float*)uni;
            dim3 g((nb * NN) / 64, CO / 64);
            k_gemm_pair<C, CO><<<g, 256, 0, stream>>>(F, FS, b0, wtA, wtD, Yc, outp);
            constexpr int PPB = 4 * (64 / (CO / 4));
            k_gather<CO><<<(nb * NN) / PPB, 256, 0, stream>>>(Yc, idx, sc, bi, outp, b0);
        }
    };

    layer(std::integral_constant<int, 3>{},   std::integral_constant<int, 64>{},  xt,         3,   wtA1, wtD1, s1, b1, xcat + 0);
    layer(std::integral_constant<int, 64>{},  std::integral_constant<int, 64>{},  xcat + 0,   512, wtA2, wtD2, s2, b2, xcat + 64);
    layer(std::integral_constant<int, 64>{},  std::integral_constant<int, 128>{}, xcat + 64,  512, wtA3, wtD3, s3, b3, xcat + 128);
    layer(std::integral_constant<int, 128>{}, std::integral_constant<int, 256>{}, xcat + 128, 512, wtA4, wtD4, s4, b4, xcat + 256);

    // head
    dim3 gt(1024 / 64, 512 / 64);
    k_transpose_w_tiled<<<gt, 256, 0, stream>>>(w5, w5t, 1024, 512);
    dim3 g5((BB * NN) / 128, 1024 / 128);
    k_conv5<<<g5, 256, 0, stream>>>(xcat, w5t, s5, b5, pmax, psum);
    k_poolreduce<<<(BB * 1024 + 255) / 256, 256, 0, stream>>>(pmax, psum, pooled);
    k_fcw<2048, true,  true ><<<(BB * 512) / 4, 256, 0, stream>>>(pooled, fc1w, s6, b6, f1, 512);
    k_fcw<512,  true,  true ><<<(BB * 256) / 4, 256, 0, stream>>>(f1, fc2w, s7, b7, f2, 256);
    k_fcw<256,  false, false><<<(BB * 40)  / 4, 256, 0, stream>>>(f2, fc3w, nullptr, fc3b, out, 40);
}

// Round 8
// 1061.105 us; speedup vs baseline: 7.4093x; 7.4093x over previous
//
#include <hip/hip_runtime.h>
#include <float.h>
#include <type_traits>

#define BB 8
#define NN 2048
#define KNN 20

__device__ __forceinline__ float leaky(float v) { return fmaxf(v, 0.2f * v); }

// ---------- transpose x (B,3,N) -> xt (B,N,3) ----------
__global__ void k_transpose_x(const float* __restrict__ x, float* __restrict__ xt) {
    int i = blockIdx.x * 256 + threadIdx.x;
    if (i >= BB * NN * 3) return;
    int c = i % 3; int n = (i / 3) % NN; int b = i / (3 * NN);
    xt[i] = x[((size_t)b * 3 + c) * NN + n];
}

// ---------- LDS-tiled transpose w (CO,CI) -> wt (CI,CO), 64x64 tiles ----------
__global__ __launch_bounds__(256) void k_transpose_w_tiled(const float* __restrict__ w,
                                                           float* __restrict__ wt,
                                                           int CO, int CI) {
    __shared__ float tile[64][65];
    int o0 = blockIdx.x * 64;
    int c0 = blockIdx.y * 64;
    int tid = threadIdx.x;
    for (int i = tid; i < 64 * 64; i += 256) {
        int r = i >> 6, c = i & 63;
        tile[r][c] = w[(size_t)(o0 + r) * CI + c0 + c];
    }
    __syncthreads();
    for (int i = tid; i < 64 * 64; i += 256) {
        int cc = i >> 6, oo = i & 63;
        wt[(size_t)(c0 + cc) * CO + o0 + oo] = tile[oo][cc];
    }
}

// ---------- all 4 edgeconv weight splits in ONE dispatch ----------
__device__ __forceinline__ void wpair_one(const float* __restrict__ w, float* __restrict__ wtA,
                                          float* __restrict__ wtD, int CO, int CI, int i) {
    int o = i / CI, c = i % CI;
    float a = w[(size_t)o * 2 * CI + c];
    float bb = w[(size_t)o * 2 * CI + CI + c];
    wtA[c * CO + o] = a;
    wtD[c * CO + o] = bb - a;
}
__global__ void k_wpair_all(const float* w1, const float* w2, const float* w3, const float* w4,
                            float* A1, float* D1, float* A2, float* D2,
                            float* A3, float* D3, float* A4, float* D4) {
    int i = blockIdx.x * 256 + threadIdx.x;
    if (i < 192)            { wpair_one(w1, A1, D1, 64, 3, i); }
    else if (i < 4288)      { wpair_one(w2, A2, D2, 64, 64, i - 192); }
    else if (i < 12480)     { wpair_one(w3, A3, D3, 128, 64, i - 4288); }
    else if (i < 45248)     { wpair_one(w4, A4, D4, 256, 128, i - 12480); }
}

// ---------- squared norms per point ----------
template<int C>
__global__ void k_xx(const float* __restrict__ F, int FS, float* __restrict__ xx) {
    int i = blockIdx.x * 256 + threadIdx.x;
    if (i >= BB * NN) return;
    const float* r = F + (size_t)i * FS;
    float s = 0.f;
    #pragma unroll
    for (int c = 0; c < C; ++c) { float v = r[c]; s += v * v; }
    xx[i] = s;
}

// ---------- distance matrix, small-C (C=3): 64x64 tile ----------
template<int C>
__global__ __launch_bounds__(256) void k_dist(const float* __restrict__ F, int FS,
                                              const float* __restrict__ xx, int b0,
                                              float* __restrict__ D) {
    __shared__ __align__(16) float Xi[C * 64];
    __shared__ __align__(16) float Xj[C * 64];
    int tid = threadIdx.x;
    int bl = blockIdx.x >> 10;
    int t  = blockIdx.x & 1023;
    int i0 = (t >> 5) * 64, j0 = (t & 31) * 64;
    int b = b0 + bl;
    const float* Fb = F + (size_t)b * NN * FS;
    int ty = tid >> 4, tx = tid & 15;
    float acc[4][4] = {};
    for (int k = tid; k < 64 * C; k += 256) {
        int r = k & 63, c = k >> 6;
        Xi[c * 64 + r] = Fb[(size_t)(i0 + r) * FS + c];
        Xj[c * 64 + r] = Fb[(size_t)(j0 + r) * FS + c];
    }
    __syncthreads();
    for (int c = 0; c < C; ++c) {
        float a[4], bv[4];
        *(float4*)a  = *(const float4*)&Xi[c * 64 + 4 * ty];
        *(float4*)bv = *(const float4*)&Xj[c * 64 + 4 * tx];
        #pragma unroll
        for (int r = 0; r < 4; ++r)
            #pragma unroll
            for (int s = 0; s < 4; ++s) acc[r][s] += a[r] * bv[s];
    }
    const float* xxb = xx + (size_t)b * NN;
    float xxi[4], xxj[4];
    #pragma unroll
    for (int r = 0; r < 4; ++r) xxi[r] = xxb[i0 + 4 * ty + r];
    #pragma unroll
    for (int s = 0; s < 4; ++s) xxj[s] = xxb[j0 + 4 * tx + s];
    float* Dp = D + (size_t)bl * NN * NN;
    #pragma unroll
    for (int r = 0; r < 4; ++r) {
        float ov[4];
        #pragma unroll
        for (int s = 0; s < 4; ++s) ov[s] = 2.f * acc[r][s] - xxi[r] - xxj[s];
        *(float4*)(Dp + (size_t)(i0 + 4 * ty + r) * NN + j0 + 4 * tx) = *(float4*)ov;
    }
}

// ---------- distance matrix, big-C (64/128): 128x128 tile, 8x8 micro-tile ----------
// All LDS reads at 16B lane stride (row/col groups {4*t, 64+4*t}) -> 2-way = free.
template<int C>
__global__ __launch_bounds__(256) void k_dist128(const float* __restrict__ F, int FS,
                                                 const float* __restrict__ xx, int b0,
                                                 float* __restrict__ D) {
    constexpr int NCH = C / 32;
    __shared__ __align__(16) float Xi[32 * 128];
    __shared__ __align__(16) float Xj[32 * 128];
    int tid = threadIdx.x;
    int ty = tid >> 4, tx = tid & 15;
    int bl = blockIdx.x >> 8;            // 256 tiles per batch (16x16)
    int t  = blockIdx.x & 255;
    int i0 = (t >> 4) * 128, j0 = (t & 15) * 128;
    int b = b0 + bl;
    const float* Fb = F + (size_t)b * NN * FS;
    float acc[8][8] = {};
    for (int ch = 0; ch < NCH; ++ch) {
        int cb = ch * 32;
        if (ch) __syncthreads();
        for (int k = tid; k < 128 * 8; k += 256) {
            int r = k & 127, cc = k >> 7;
            float vi[4], vj[4];
            *(float4*)vi = *(const float4*)(Fb + (size_t)(i0 + r) * FS + cb + 4 * cc);
            *(float4*)vj = *(const float4*)(Fb + (size_t)(j0 + r) * FS + cb + 4 * cc);
            #pragma unroll
            for (int u = 0; u < 4; ++u) {
                Xi[(4 * cc + u) * 128 + r] = vi[u];
                Xj[(4 * cc + u) * 128 + r] = vj[u];
            }
        }
        __syncthreads();
        for (int c = 0; c < 32; ++c) {
            float a0[4], a1[4], w0[4], w1[4];
            *(float4*)a0 = *(const float4*)&Xi[c * 128 + 4 * ty];
            *(float4*)a1 = *(const float4*)&Xi[c * 128 + 64 + 4 * ty];
            *(float4*)w0 = *(const float4*)&Xj[c * 128 + 4 * tx];
            *(float4*)w1 = *(const float4*)&Xj[c * 128 + 64 + 4 * tx];
            #pragma unroll
            for (int r = 0; r < 4; ++r)
                #pragma unroll
                for (int s = 0; s < 4; ++s) {
                    acc[r][s]         += a0[r] * w0[s];
                    acc[r][4 + s]     += a0[r] * w1[s];
                    acc[4 + r][s]     += a1[r] * w0[s];
                    acc[4 + r][4 + s] += a1[r] * w1[s];
                }
        }
    }
    const float* xxb = xx + (size_t)b * NN;
    float xxi[8], xxj[8];
    #pragma unroll
    for (int r = 0; r < 4; ++r) {
        xxi[r]     = xxb[i0 + 4 * ty + r];
        xxi[4 + r] = xxb[i0 + 64 + 4 * ty + r];
        xxj[r]     = xxb[j0 + 4 * tx + r];
        xxj[4 + r] = xxb[j0 + 64 + 4 * tx + r];
    }
    float* Dp = D + (size_t)bl * NN * NN;
    #pragma unroll
    for (int r = 0; r < 8; ++r) {
        int row = i0 + (r < 4 ? 4 * ty + r : 64 + 4 * ty + (r - 4));
        float ov0[4], ov1[4];
        #pragma unroll
        for (int s = 0; s < 4; ++s) {
            ov0[s] = 2.f * acc[r][s]     - xxi[r] - xxj[s];
            ov1[s] = 2.f * acc[r][4 + s] - xxi[r] - xxj[4 + s];
        }
        *(float4*)(Dp + (size_t)row * NN + j0 + 4 * tx)      = *(float4*)ov0;
        *(float4*)(Dp + (size_t)row * NN + j0 + 64 + 4 * tx) = *(float4*)ov1;
    }
}

// ---------- top-20 selection: one wave per query, row in registers ----------
__global__ __launch_bounds__(256) void k_select(const float* __restrict__ D,
                                                int* __restrict__ idxo, int b0) {
    int tid = threadIdx.x;
    int lane = tid & 63;
    int w = (blockIdx.x << 2) + (tid >> 6);
    int bl = w / NN, n = w % NN;
    const float* row = D + (size_t)w * NN;
    float d[32];
    #pragma unroll
    for (int q = 0; q < 8; ++q)
        *(float4*)&d[4 * q] = *(const float4*)(row + 4 * lane + 256 * q);
    float bv = d[0]; int bj = 0;
    #pragma unroll
    for (int j = 1; j < 32; ++j) if (d[j] > bv) { bv = d[j]; bj = j; }
    int* op = idxo + ((size_t)(b0 + bl) * NN + n) * KNN;
    for (int k = 0; k < KNN; ++k) {
        float rv = bv;
        int rm = 4 * lane + 256 * (bj >> 2) + (bj & 3);
        #pragma unroll
        for (int s = 1; s < 64; s <<= 1) {
            float ov = __shfl_xor(rv, s);
            int om = __shfl_xor(rm, s);
            if (ov > rv || (ov == rv && om < rm)) { rv = ov; rm = om; }
        }
        if (lane == 0) op[k] = rm;
        if (((rm >> 2) & 63) == lane) {
            int oj = ((rm >> 8) << 2) | (rm & 3);
            #pragma unroll
            for (int j = 0; j < 32; ++j) if (j == oj) d[j] = -FLT_MAX;
            bv = d[0]; bj = 0;
            #pragma unroll
            for (int j = 1; j < 32; ++j) if (d[j] > bv) { bv = d[j]; bj = j; }
        }
    }
}

// ---------- pair GEMM: Y = F*wtA (union buffer), C2 = F*wtD -> written straight
// into the layer's xcat output slot (stride 512); gather reads+overwrites it ----------
template<int CIN, int COUT>
__global__ __launch_bounds__(256) void k_gemm_pair(const float* __restrict__ F, int FS, int b0,
    const float* __restrict__ wtA, const float* __restrict__ wtD,
    float* __restrict__ Y, float* __restrict__ c2x) {
    constexpr int CCH = (CIN >= 32) ? 32 : CIN;
    constexpr int NCH = CIN / CCH;
    __shared__ __align__(16) float Xi[CCH * 64];
    __shared__ __align__(16) float Wa[CCH * 64];
    __shared__ __align__(16) float Wd[CCH * 64];
    int tid = threadIdx.x;
    int r0 = blockIdx.x * 64;            // chunk-local row
    int c0 = blockIdx.y * 64;
    int b = b0 + r0 / NN;
    int n0 = r0 % NN;
    const float* Fb = F + ((size_t)b * NN + n0) * FS;
    int ty = tid >> 4, tx = tid & 15;
    float accY[4][4] = {}, accD[4][4] = {};
    for (int ch = 0; ch < NCH; ++ch) {
        int cb = ch * CCH;
        if (ch) __syncthreads();
        if constexpr (CCH % 4 == 0) {
            for (int t = tid; t < 64 * (CCH / 4); t += 256) {
                int r = t & 63, cc = t >> 6;
                float v[4];
                *(float4*)v = *(const float4*)(Fb + (size_t)r * FS + cb + 4 * cc);
                #pragma unroll
                for (int u = 0; u < 4; ++u) Xi[(4 * cc + u) * 64 + r] = v[u];
            }
            for (int t = tid; t < CCH * 16; t += 256) {
                int c = t >> 4, q = t & 15;
                *(float4*)&Wa[c * 64 + 4 * q] = *(const float4*)(wtA + (size_t)(cb + c) * COUT + c0 + 4 * q);
                *(float4*)&Wd[c * 64 + 4 * q] = *(const float4*)(wtD + (size_t)(cb + c) * COUT + c0 + 4 * q);
            }
        } else {
            for (int t = tid; t < 64 * CCH; t += 256) {
                int r = t & 63, c = t >> 6;
                Xi[c * 64 + r] = Fb[(size_t)r * FS + cb + c];
            }
            for (int t = tid; t < CCH * 64; t += 256) {
                int col = t & 63, c = t >> 6;
                Wa[c * 64 + col] = wtA[(size_t)(cb + c) * COUT + c0 + col];
                Wd[c * 64 + col] = wtD[(size_t)(cb + c) * COUT + c0 + col];
            }
        }
        __syncthreads();
        for (int c = 0; c < CCH; ++c) {
            float a[4], wa[4], wd[4];
            *(float4*)a  = *(const float4*)&Xi[c * 64 + 4 * ty];
            *(float4*)wa = *(const float4*)&Wa[c * 64 + 4 * tx];
            *(float4*)wd = *(const float4*)&Wd[c * 64 + 4 * tx];
            #pragma unroll
            for (int r = 0; r < 4; ++r)
                #pragma unroll
                for (int s = 0; s < 4; ++s) {
                    accY[r][s] += a[r] * wa[s];
                    accD[r][s] += a[r] * wd[s];
                }
        }
    }
    #pragma unroll
    for (int r = 0; r < 4; ++r) {
        *(float4*)(Y + (size_t)(r0 + 4 * ty + r) * COUT + c0 + 4 * tx) = *(float4*)accY[r];
        *(float4*)(c2x + ((size_t)b0 * NN + r0 + 4 * ty + r) * 512 + c0 + 4 * tx) = *(float4*)accD[r];
    }
}

// ---------- gather-max: io slot holds C2 on entry, final features on exit ----------
template<int COUT>
__global__ __launch_bounds__(256) void k_gather(const float* __restrict__ Y,
    const int* __restrict__ idx, const float* __restrict__ sc, const float* __restrict__ bi,
    float* io, int b0) {
    constexpr int LPP = COUT / 4;
    constexpr int PPW = 64 / LPP;
    constexpr int PPB = 4 * PPW;
    int tid = threadIdx.x;
    int lane = tid & 63, wv = tid >> 6;
    int pl = blockIdx.x * PPB + wv * PPW + lane / LPP;   // chunk-local point
    int bl = pl / NN, n = pl % NN;
    int o0 = 4 * (lane % LPP);
    float* iop = io + ((size_t)(b0 + bl) * NN + n) * 512 + o0;
    float c2[4], s4[4], b4[4];
    *(float4*)c2 = *(const float4*)iop;
    *(float4*)s4 = *(const float4*)(sc + o0);
    *(float4*)b4 = *(const float4*)(bi + o0);
    const int* ip = idx + ((size_t)(b0 + bl) * NN + n) * KNN;
    const float* Yb = Y + (size_t)bl * NN * COUT;
    float mx[4] = {-FLT_MAX, -FLT_MAX, -FLT_MAX, -FLT_MAX};
    for (int k = 0; k < KNN; ++k) {
        int m = ip[k];
        float y[4];
        *(float4*)y = *(const float4*)(Yb + (size_t)m * COUT + o0);
        #pragma unroll
        for (int u = 0; u < 4; ++u) {
            float v = (y[u] + c2[u]) * s4[u] + b4[u];
            mx[u] = fmaxf(mx[u], leaky(v));
        }
    }
    *(float4*)iop = *(float4*)mx;
}

// ---------- conv5: 128x128 tile, 8x8 micro-tile, fused partial pooling ----------
__global__ __launch_bounds__(256) void k_conv5(const float* __restrict__ xcat,
    const float* __restrict__ w5t, const float* __restrict__ s5, const float* __restrict__ b5,
    float* __restrict__ pmax, float* __restrict__ psum) {
    __shared__ __align__(16) float Xi[32 * 128];
    __shared__ __align__(16) float Wj[32 * 128];
    int tid = threadIdx.x;
    int ty = tid >> 4, tx = tid & 15;
    int r0 = blockIdx.x * 128;
    int col0 = blockIdx.y * 128;
    int b = r0 / NN, tileInB = (r0 % NN) / 128;
    const float* Fb = xcat + (size_t)r0 * 512;
    float acc[8][8] = {};
    for (int ch = 0; ch < 16; ++ch) {
        int cb = ch * 32;
        if (ch) __syncthreads();
        for (int t = tid; t < 128 * 8; t += 256) {
            int r = t & 127, cc = t >> 7;
            float v[4];
            *(float4*)v = *(const float4*)(Fb + (size_t)r * 512 + cb + 4 * cc);
            #pragma unroll
            for (int u = 0; u < 4; ++u) Xi[(4 * cc + u) * 128 + r] = v[u];
        }
        for (int t = tid; t < 32 * 32; t += 256) {
            int c = t >> 5, q = t & 31;
            *(float4*)&Wj[c * 128 + 4 * q] = *(const float4*)(w5t + (size_t)(cb + c) * 1024 + col0 + 4 * q);
        }
        __syncthreads();
        for (int c = 0; c < 32; ++c) {
            float a0[4], a1[4], w0[4], w1[4];
            *(float4*)a0 = *(const float4*)&Xi[c * 128 + 4 * ty];
            *(float4*)a1 = *(const float4*)&Xi[c * 128 + 64 + 4 * ty];
            *(float4*)w0 = *(const float4*)&Wj[c * 128 + 4 * tx];
            *(float4*)w1 = *(const float4*)&Wj[c * 128 + 64 + 4 * tx];
            #pragma unroll
            for (int r = 0; r < 4; ++r)
                #pragma unroll
                for (int u = 0; u < 4; ++u) {
                    acc[r][u]         += a0[r] * w0[u];
                    acc[r][4 + u]     += a0[r] * w1[u];
                    acc[4 + r][u]     += a1[r] * w0[u];
                    acc[4 + r][4 + u] += a1[r] * w1[u];
                }
        }
    }
    float hmx[2][4], hsm[2][4];
    #pragma unroll
    for (int h = 0; h < 2; ++h)
        #pragma unroll
        for (int u = 0; u < 4; ++u) { hmx[h][u] = -FLT_MAX; hsm[h][u] = 0.f; }
    #pragma unroll
    for (int h = 0; h < 2; ++h)
        #pragma unroll
        for (int u = 0; u < 4; ++u) {
            int o = col0 + 64 * h + 4 * tx + u;
            float sv = s5[o], bv = b5[o];
            #pragma unroll
            for (int r = 0; r < 8; ++r) {
                float hh = leaky(acc[r][4 * h + u] * sv + bv);
                hmx[h][u] = fmaxf(hmx[h][u], hh);
                hsm[h][u] += hh;
            }
        }
    __syncthreads();
    float* redM = Xi;
    float* redS = Wj;
    #pragma unroll
    for (int h = 0; h < 2; ++h) {
        *(float4*)&redM[ty * 128 + 64 * h + 4 * tx] = *(float4*)hmx[h];
        *(float4*)&redS[ty * 128 + 64 * h + 4 * tx] = *(float4*)hsm[h];
    }
    __syncthreads();
    for (int s = 8; s > 0; s >>= 1) {
        if (ty < s) {
            #pragma unroll
            for (int h = 0; h < 2; ++h) {
                int c = 64 * h + 4 * tx;
                float m0[4], m1[4], s0[4], s1[4];
                *(float4*)m0 = *(float4*)&redM[ty * 128 + c];
                *(float4*)m1 = *(float4*)&redM[(ty + s) * 128 + c];
                *(float4*)s0 = *(float4*)&redS[ty * 128 + c];
                *(float4*)s1 = *(float4*)&redS[(ty + s) * 128 + c];
                #pragma unroll
                for (int u = 0; u < 4; ++u) { m0[u] = fmaxf(m0[u], m1[u]); s0[u] += s1[u]; }
                *(float4*)&redM[ty * 128 + c] = *(float4*)m0;
                *(float4*)&redS[ty * 128 + c] = *(float4*)s0;
            }
        }
        __syncthreads();
    }
    if (ty == 0) {
        #pragma unroll
        for (int h = 0; h < 2; ++h) {
            int c = 64 * h + 4 * tx;
            size_t o = ((size_t)b * 16 + tileInB) * 1024 + col0 + c;
            *(float4*)&pmax[o] = *(float4*)&redM[c];
            *(float4*)&psum[o] = *(float4*)&redS[c];
        }
    }
}

__global__ void k_poolreduce(const float* __restrict__ pmax, const float* __restrict__ psum,
                             float* __restrict__ pooled) {
    int i = blockIdx.x * 256 + threadIdx.x;
    if (i >= BB * 1024) return;
    int b = i / 1024, o = i % 1024;
    float mx = -FLT_MAX, sm = 0.f;
    for (int ch = 0; ch < 16; ++ch) {
        mx = fmaxf(mx, pmax[((size_t)b * 16 + ch) * 1024 + o]);
        sm += psum[((size_t)b * 16 + ch) * 1024 + o];
    }
    pooled[(size_t)b * 2048 + o] = mx;
    pooled[(size_t)b * 2048 + 1024 + o] = sm / (float)NN;
}

// ---------- FC: wave-per-output, coalesced float4 weight reads, shfl reduce ----------
template<int CI, bool SCALE, bool RELU>
__global__ __launch_bounds__(256) void k_fcw(const float* __restrict__ in,
                                             const float* __restrict__ w,
                                             const float* __restrict__ sc,
                                             const float* __restrict__ bi,
                                             float* __restrict__ out, int CO) {
    int wv = (blockIdx.x << 2) + (threadIdx.x >> 6);
    int lane = threadIdx.x & 63;
    int o = wv % CO, b = wv / CO;
    const float* ir = in + (size_t)b * CI;
    const float* wr = w + (size_t)o * CI;
    float acc = 0.f;
    #pragma unroll
    for (int q = 0; q < CI / 256; ++q) {
        int ofs = q * 256 + 4 * lane;
        float4 wv4 = *(const float4*)(wr + ofs);
        float4 iv4 = *(const float4*)(ir + ofs);
        acc += wv4.x * iv4.x + wv4.y * iv4.y + wv4.z * iv4.z + wv4.w * iv4.w;
    }
    #pragma unroll
    for (int s = 1; s < 64; s <<= 1) acc += __shfl_xor(acc, s);
    if (lane == 0) {
        float v = SCALE ? (acc * sc[o] + bi[o]) : (acc + bi[o]);
        if (RELU) v = fmaxf(v, 0.f);
        out[wv] = v;
    }
}

extern "C" void kernel_launch(void* const* d_in, const int* in_sizes, int n_in,
                              void* d_out, int out_size, void* d_ws, size_t ws_size,
                              hipStream_t stream) {
    const float* x    = (const float*)d_in[0];
    const float* w1   = (const float*)d_in[1];
    const float* s1   = (const float*)d_in[2];
    const float* b1   = (const float*)d_in[3];
    const float* w2   = (const float*)d_in[4];
    const float* s2   = (const float*)d_in[5];
    const float* b2   = (const float*)d_in[6];
    const float* w3   = (const float*)d_in[7];
    const float* s3   = (const float*)d_in[8];
    const float* b3   = (const float*)d_in[9];
    const float* w4   = (const float*)d_in[10];
    const float* s4   = (const float*)d_in[11];
    const float* b4   = (const float*)d_in[12];
    const float* w5   = (const float*)d_in[13];
    const float* s5   = (const float*)d_in[14];
    const float* b5   = (const float*)d_in[15];
    const float* fc1w = (const float*)d_in[16];
    const float* s6   = (const float*)d_in[17];
    const float* b6   = (const float*)d_in[18];
    const float* fc2w = (const float*)d_in[19];
    const float* s7   = (const float*)d_in[20];
    const float* b7   = (const float*)d_in[21];
    const float* fc3w = (const float*)d_in[22];
    const float* fc3b = (const float*)d_in[23];
    float* out = (float*)d_out;

    char* ws = (char*)d_ws;
    size_t off = 0;
    auto alloc = [&](size_t bytes) {
        void* p = ws + off;
        off = (off + bytes + 255) & ~(size_t)255;
        return p;
    };
    float* xt   = (float*)alloc((size_t)BB * NN * 3 * 4);
    float* xcat = (float*)alloc((size_t)BB * NN * 512 * 4);
    int*   idx  = (int*)  alloc((size_t)BB * NN * KNN * 4);
    float* xx   = (float*)alloc((size_t)BB * NN * 4);
    float* wtA1 = (float*)alloc(3 * 64 * 4);
    float* wtD1 = (float*)alloc(3 * 64 * 4);
    float* wtA2 = (float*)alloc(64 * 64 * 4);
    float* wtD2 = (float*)alloc(64 * 64 * 4);
    float* wtA3 = (float*)alloc(64 * 128 * 4);
    float* wtD3 = (float*)alloc(64 * 128 * 4);
    float* wtA4 = (float*)alloc(128 * 256 * 4);
    float* wtD4 = (float*)alloc(128 * 256 * 4);
    size_t base_end = off;

    // UNION region: D (dist phase, per-batch chunks) / Y (transform) / head buffers
    const size_t D1 = (size_t)NN * NN * 4;
    size_t avail = ws_size > base_end ? ws_size - base_end : 0;
    int nbD = (int)(avail / D1);
    if (nbD < 1) nbD = 1;
    if (nbD > BB) nbD = BB;
    char* uni = ws + base_end;
    float* D      = (float*)uni;
    float* w5t    = (float*)uni;
    float* pmax   = w5t + 512 * 1024;
    float* psum   = pmax + (size_t)BB * 16 * 1024;
    float* pooled = psum + (size_t)BB * 16 * 1024;
    float* f1     = pooled + (size_t)BB * 2048;
    float* f2     = f1 + (size_t)BB * 512;

    k_transpose_x<<<(BB * NN * 3 + 255) / 256, 256, 0, stream>>>(x, xt);
    k_wpair_all<<<(45248 + 255) / 256, 256, 0, stream>>>(w1, w2, w3, w4,
        wtA1, wtD1, wtA2, wtD2, wtA3, wtD3, wtA4, wtD4);

    auto layer = [&](auto cTag, auto coTag, const float* F, int FS,
                     const float* wtA, const float* wtD,
                     const float* sc, const float* bi, float* outp) {
        constexpr int C  = decltype(cTag)::value;
        constexpr int CO = decltype(coTag)::value;
        k_xx<C><<<(BB * NN + 255) / 256, 256, 0, stream>>>(F, FS, xx);
        for (int b0 = 0; b0 < BB; b0 += nbD) {
            int nb = BB - b0 < nbD ? BB - b0 : nbD;
            if constexpr (C >= 32) {
                k_dist128<C><<<nb * 256, 256, 0, stream>>>(F, FS, xx, b0, D);
            } else {
                k_dist<C><<<nb * 1024, 256, 0, stream>>>(F, FS, xx, b0, D);
            }
            k_select<<<nb * 512, 256, 0, stream>>>(D, idx, b0);
        }
        // transform + gather: Y-only union buffer (C2 goes straight into xcat)
        size_t ypb = (size_t)NN * CO * 4;
        int nbY = (int)(avail / ypb);
        if (nbY < 1) nbY = 1;
        if (nbY > BB) nbY = BB;
        for (int b0 = 0; b0 < BB; b0 += nbY) {
            int nb = BB - b0 < nbY ? BB - b0 : nbY;
            float* Yc = (float*)uni;
            dim3 g((nb * NN) / 64, CO / 64);
            k_gemm_pair<C, CO><<<g, 256, 0, stream>>>(F, FS, b0, wtA, wtD, Yc, outp);
            constexpr int PPB = 4 * (64 / (CO / 4));
            k_gather<CO><<<(nb * NN) / PPB, 256, 0, stream>>>(Yc, idx, sc, bi, outp, b0);
        }
    };

    layer(std::integral_constant<int, 3>{},   std::integral_constant<int, 64>{},  xt,         3,   wtA1, wtD1, s1, b1, xcat + 0);
    layer(std::integral_constant<int, 64>{},  std::integral_constant<int, 64>{},  xcat + 0,   512, wtA2, wtD2, s2, b2, xcat + 64);
    layer(std::integral_constant<int, 64>{},  std::integral_constant<int, 128>{}, xcat + 64,  512, wtA3, wtD3, s3, b3, xcat + 128);
    layer(std::integral_constant<int, 128>{}, std::integral_constant<int, 256>{}, xcat + 128, 512, wtA4, wtD4, s4, b4, xcat + 256);

    // head (union region now holds w5t/pmax/psum/pooled/f1/f2)
    dim3 gt(1024 / 64, 512 / 64);
    k_transpose_w_tiled<<<gt, 256, 0, stream>>>(w5, w5t, 1024, 512);
    dim3 g5((BB * NN) / 128, 1024 / 128);
    k_conv5<<<g5, 256, 0, stream>>>(xcat, w5t, s5, b5, pmax, psum);
    k_poolreduce<<<(BB * 1024 + 255) / 256, 256, 0, stream>>>(pmax, psum, pooled);
    k_fcw<2048, true,  true ><<<(BB * 512) / 4, 256, 0, stream>>>(pooled, fc1w, s6, b6, f1, 512);
    k_fcw<512,  true,  true ><<<(BB * 256) / 4, 256, 0, stream>>>(f1, fc2w, s7, b7, f2, 256);
    k_fcw<256,  false, false><<<(BB * 40)  / 4, 256, 0, stream>>>(f2, fc3w, nullptr, fc3b, out, 40);
}